// Round 5
// baseline (86718.787 us; speedup 1.0000x reference)
//
#include <hip/hip_runtime.h>
#include <cstdint>

#define V 32000
#define E 128
#define H 1024
#define T 64
#define B 32
#define BH (B * H)

using u64 = unsigned long long;
using u32 = unsigned int;

__device__ __forceinline__ float sigm(float x) { return 1.f / (1.f + expf(-x)); }

// ---- agent-scope (cross-XCD coherent) ops: bypass per-XCD L2, no cache flushes ----
__device__ __forceinline__ float2 ald2(const float* p) {
  u64 v = __hip_atomic_load((const u64*)p, __ATOMIC_RELAXED, __HIP_MEMORY_SCOPE_AGENT);
  union { u64 u; float2 f; } x; x.u = v; return x.f;
}
__device__ __forceinline__ u64 ald64(const u64* p) {
  return __hip_atomic_load(p, __ATOMIC_RELAXED, __HIP_MEMORY_SCOPE_AGENT);
}
__device__ __forceinline__ void ast(float* p, float v) {
  __hip_atomic_store(p, v, __ATOMIC_RELAXED, __HIP_MEMORY_SCOPE_AGENT);
}
__device__ __forceinline__ void ast64(u64* p, u64 v) {
  __hip_atomic_store(p, v, __ATOMIC_RELAXED, __HIP_MEMORY_SCOPE_AGENT);
}

// tf_mask arrives as u8 bools or i32; i32 layout never has nonzero bytes at i%4!=0.
__device__ __forceinline__ u64 decode_tfmask(const unsigned char* __restrict__ raw) {
  int cnt = 0;
  for (int i = 0; i < 64; ++i)
    if ((i & 3) && raw[i]) cnt++;
  u64 bits = 0;
  if (cnt > 0) {
    for (int i = 0; i < 64; ++i) bits |= (u64)(raw[i] ? 1 : 0) << i;
  } else {
    const int* r = (const int*)raw;
    for (int i = 0; i < 64; ++i) bits |= (u64)(r[i] ? 1 : 0) << i;
  }
  return bits;
}

// ---- lightweight grid barrier: monotonic counter, no cache invalidation ----
__device__ __forceinline__ void gbar(u32* bar, u32 ph) {
  asm volatile("s_waitcnt vmcnt(0)" ::: "memory");   // my stores are at the coherence point
  __syncthreads();
  if (threadIdx.x == 0) {
    __hip_atomic_fetch_add(bar, 1u, __ATOMIC_RELAXED, __HIP_MEMORY_SCOPE_AGENT);
    const u32 tgt = ph * gridDim.x;
    while (__hip_atomic_load(bar, __ATOMIC_RELAXED, __HIP_MEMORY_SCOPE_AGENT) < tgt)
      __builtin_amdgcn_s_sleep(8);
  }
  __syncthreads();
}

// ---------------- LDS layout (floats) ----------------
#define ZS_STRIDE 260
#define SMEM_FLOATS (32 * ZS_STRIDE + 256 + 64)

// 4-gate partial dots over one staged chunk. wb = w + unit*WS + kc; gate stride H*WS.
template <int KC, int WS>
__device__ __forceinline__ void accum_chunk(const float* __restrict__ zs,
                                            const float* __restrict__ wb,
                                            int b, int kq, float acc[4]) {
  constexpr int KQ = KC / 4;
  const float* zrow = zs + b * ZS_STRIDE + kq * KQ;
  const float* wq = wb + kq * KQ;
  #pragma unroll
  for (int ks = 0; ks < KQ; ks += 16) {
    const float4 z0 = *(const float4*)(zrow + ks);
    const float4 z1 = *(const float4*)(zrow + ks + 4);
    const float4 z2 = *(const float4*)(zrow + ks + 8);
    const float4 z3 = *(const float4*)(zrow + ks + 12);
    #pragma unroll
    for (int g = 0; g < 4; ++g) {
      const float* wp = wq + (size_t)g * (size_t)H * WS + ks;
      const float4 w0 = *(const float4*)(wp);
      const float4 w1 = *(const float4*)(wp + 4);
      const float4 w2 = *(const float4*)(wp + 8);
      const float4 w3 = *(const float4*)(wp + 12);
      acc[g] += z0.x * w0.x + z0.y * w0.y + z0.z * w0.z + z0.w * w0.w
              + z1.x * w1.x + z1.y * w1.y + z1.z * w1.z + z1.w * w1.w
              + z2.x * w2.x + z2.y * w2.y + z2.z * w2.z + z2.w * w2.w
              + z3.x * w3.x + z3.y * w3.y + z3.z * w3.z + z3.w * w3.w;
    }
  }
}

// LSTM cell: 32 b x 4 kq x 2 units = 256 threads; unit = w*2 + u2.
// MODE 0: x = xsrc + bb*H (an h array -> agent loads); 1: x = emb_dec[tok(bb)]; 2: x = emb_enc[src[t*B+bb]].
// first: hprev == 0 (skip phase H) and c == 0 (skip c read).
template <int KX, int MODE>
__device__ void cell_run(
    int w, int t, const float* __restrict__ xsrc,
    const int* __restrict__ src, u64 tfb, const u64* __restrict__ packed,
    const float* __restrict__ wih, const float* __restrict__ whh,
    const float* __restrict__ bih, const float* __restrict__ bhh,
    const float* __restrict__ hprev, float* __restrict__ hout,
    float* __restrict__ cio, float* __restrict__ smem, bool first) {
  float* zs = smem;
  float* part = smem + 32 * ZS_STRIDE;
  int* toks = (int*)(smem + 32 * ZS_STRIDE + 256);

  const int tid = threadIdx.x;
  const int b = tid & 31;
  const int kq = (tid >> 5) & 3;
  const int u2 = tid >> 7;
  const int unit = w * 2 + u2;
  const int bb = tid >> 3, lq = tid & 7;

  if (MODE == 1) {
    if (tid < 32) {
      int tok;
      const int tm1 = t - 1;
      if (tm1 == 0) tok = src[tid];
      else if ((tfb >> tm1) & 1) tok = src[tm1 * B + tid];
      else {
        const u64* p = packed + ((size_t)tm1 * B + tid) * 8;
        u64 m = ald64(p);
        #pragma unroll
        for (int g = 1; g < 8; ++g) { u64 x = ald64(p + g); m = m > x ? m : x; }
        tok = (int)(0xFFFFFFFFu - (unsigned)(m & 0xFFFFFFFFull));
      }
      toks[tid] = tok;
    }
    __syncthreads();
  }

  float acc[4] = {0.f, 0.f, 0.f, 0.f};

  // ---- phase X ----
  {
    const float* rowb = (MODE == 0) ? xsrc + (size_t)bb * H
                      : (MODE == 1) ? xsrc + (size_t)toks[bb] * E
                                    : xsrc + (size_t)src[t * B + bb] * E;
    constexpr int KC = (KX >= 256) ? 256 : KX;
    #pragma unroll 1
    for (int kc = 0; kc < KX; kc += KC) {
      #pragma unroll
      for (int j = lq; j < KC / 4; j += 8) {
        if (MODE == 0) {
          float2 lo = ald2(rowb + kc + 4 * j);
          float2 hi = ald2(rowb + kc + 4 * j + 2);
          *(float4*)(zs + bb * ZS_STRIDE + 4 * j) = make_float4(lo.x, lo.y, hi.x, hi.y);
        } else {
          *(float4*)(zs + bb * ZS_STRIDE + 4 * j) = *(const float4*)(rowb + kc + 4 * j);
        }
      }
      __syncthreads();
      accum_chunk<KC, KX>(zs, wih + (size_t)unit * KX + kc, b, kq, acc);
      __syncthreads();
    }
  }
  // ---- phase H (skipped when hprev == 0) ----
  if (!first) {
    const float* rowb = hprev + (size_t)bb * H;
    #pragma unroll 1
    for (int kc = 0; kc < H; kc += 256) {
      #pragma unroll
      for (int j = lq; j < 64; j += 8) {
        float2 lo = ald2(rowb + kc + 4 * j);
        float2 hi = ald2(rowb + kc + 4 * j + 2);
        *(float4*)(zs + bb * ZS_STRIDE + 4 * j) = make_float4(lo.x, lo.y, hi.x, hi.y);
      }
      __syncthreads();
      accum_chunk<256, H>(zs, whh + (size_t)unit * H + kc, b, kq, acc);
      __syncthreads();
    }
  }

  #pragma unroll
  for (int g = 0; g < 4; ++g) acc[g] += __shfl_xor(acc[g], 32);
  if (kq == 2)
    *(float4*)(part + (u2 * 32 + b) * 4) = make_float4(acc[0], acc[1], acc[2], acc[3]);
  __syncthreads();
  if (kq == 0) {
    const float4 p = *(const float4*)(part + (u2 * 32 + b) * 4);
    float gi = acc[0] + p.x + bih[unit]         + bhh[unit];
    float gf = acc[1] + p.y + bih[H + unit]     + bhh[H + unit];
    float gg = acc[2] + p.z + bih[2 * H + unit] + bhh[2 * H + unit];
    float go = acc[3] + p.w + bih[3 * H + unit] + bhh[3 * H + unit];
    float c = first ? 0.f : cio[b * H + unit];
    c = sigm(gf) * c + sigm(gi) * tanhf(gg);
    cio[b * H + unit] = c;                       // block-private: normal store
    ast(&hout[b * H + unit], sigm(go) * tanhf(c)); // cross-block: agent store
  }
  __syncthreads();
}

// ---------------- FC work unit w: v-range [w*64, w*64+64) ----------------

#define VPT 8
#define VB 64

__device__ void fc_run(int w, int t, const float* __restrict__ fc_w,
                       const float* __restrict__ fc_b, const float* __restrict__ h,
                       float* __restrict__ out, u64* __restrict__ packed,
                       float* __restrict__ smem) {
  float* hs = smem;                       // 32*132; later reused as out tile [32][68]
  u64* red = (u64*)(smem + 32 * 132);     // 8*32 u64
  const int tid = threadIdx.x;
  const int b = tid & 31;
  const int vl = tid >> 5;
  const int v0 = w * VB;

  float4 acc[VPT];
  #pragma unroll
  for (int q = 0; q < VPT; ++q) acc[q] = make_float4(0.f, 0.f, 0.f, 0.f);

  #pragma unroll 1
  for (int kc = 0; kc < H; kc += 128) {
    __syncthreads();
    {
      const int bb = tid >> 3;
      const int kk = (tid & 7) << 4;
      const float* gp = h + (size_t)bb * H + kc + kk;
      float2 v0r = ald2(gp);      float2 v1r = ald2(gp + 2);
      float2 v2r = ald2(gp + 4);  float2 v3r = ald2(gp + 6);
      float2 v4r = ald2(gp + 8);  float2 v5r = ald2(gp + 10);
      float2 v6r = ald2(gp + 12); float2 v7r = ald2(gp + 14);
      float* s = hs + bb * 132 + kk;
      *(float4*)(s)      = make_float4(v0r.x, v0r.y, v1r.x, v1r.y);
      *(float4*)(s + 4)  = make_float4(v2r.x, v2r.y, v3r.x, v3r.y);
      *(float4*)(s + 8)  = make_float4(v4r.x, v4r.y, v5r.x, v5r.y);
      *(float4*)(s + 12) = make_float4(v6r.x, v6r.y, v7r.x, v7r.y);
    }
    __syncthreads();
    const float* hb = hs + b * 132;
    #pragma unroll
    for (int ks = 0; ks < 128; ks += 16) {
      const float4 x0 = *(const float4*)(hb + ks);
      const float4 x1 = *(const float4*)(hb + ks + 4);
      const float4 x2 = *(const float4*)(hb + ks + 8);
      const float4 x3 = *(const float4*)(hb + ks + 12);
      #pragma unroll
      for (int q = 0; q < VPT; ++q) {
        const float* wp = fc_w + (size_t)(v0 + (q << 3) + vl) * H + kc + ks;
        const float4 w0 = *(const float4*)(wp);
        const float4 w1 = *(const float4*)(wp + 4);
        const float4 w2 = *(const float4*)(wp + 8);
        const float4 w3 = *(const float4*)(wp + 12);
        acc[q].x += x0.x * w0.x; acc[q].y += x0.y * w0.y; acc[q].z += x0.z * w0.z; acc[q].w += x0.w * w0.w;
        acc[q].x += x1.x * w1.x; acc[q].y += x1.y * w1.y; acc[q].z += x1.z * w1.z; acc[q].w += x1.w * w1.w;
        acc[q].x += x2.x * w2.x; acc[q].y += x2.y * w2.y; acc[q].z += x2.z * w2.z; acc[q].w += x2.w * w2.w;
        acc[q].x += x3.x * w3.x; acc[q].y += x3.y * w3.y; acc[q].z += x3.z * w3.z; acc[q].w += x3.w * w3.w;
      }
    }
  }

  u64 best = 0ull;
  float vals[VPT];
  #pragma unroll
  for (int q = 0; q < VPT; ++q) {
    const int v = v0 + (q << 3) + vl;
    float val = ((acc[q].x + acc[q].y) + (acc[q].z + acc[q].w)) + fc_b[v];
    vals[q] = val;
    unsigned uu = __float_as_uint(val);
    uu = (uu & 0x80000000u) ? ~uu : (uu | 0x80000000u);
    u64 pk = ((u64)uu << 32) | (u64)(0xFFFFFFFFu - (unsigned)v);  // ties -> smallest v
    best = best > pk ? best : pk;
  }
  red[vl * 32 + b] = best;
  __syncthreads();

  float* tile = hs;                        // [32][68]
  #pragma unroll
  for (int q = 0; q < VPT; ++q) tile[b * 68 + (q << 3) + vl] = vals[q];

  if (tid < 32) {
    u64 m = red[tid];
    #pragma unroll
    for (int q = 1; q < 8; ++q) { u64 x = red[q * 32 + tid]; m = m > x ? m : x; }
    atomicMax(&packed[((size_t)t * B + tid) * 8 + (w & 7)], m);  // device-scope
  }
  __syncthreads();
  {
    const int bb = tid >> 3, j = tid & 7;
    const float4 o0 = *(const float4*)(tile + bb * 68 + j * 8);
    const float4 o1 = *(const float4*)(tile + bb * 68 + j * 8 + 4);
    float* op = out + (size_t)t * (B * V) + (size_t)bb * V + v0 + j * 8;
    *(float4*)op = o0;
    *(float4*)(op + 4) = o1;
  }
  __syncthreads();
}

// ---------------- persistent cooperative mega-kernel, custom barriers ----------------

__global__ __launch_bounds__(256, 2) void mega(
    const int* __restrict__ src, const unsigned char* __restrict__ tfm,
    const float* __restrict__ emb_enc, const float* __restrict__ emb_dec,
    const float* __restrict__ fc_w, const float* __restrict__ fc_b,
    const float* __restrict__ e_wih0, const float* __restrict__ e_whh0,
    const float* __restrict__ e_bih0, const float* __restrict__ e_bhh0,
    const float* __restrict__ e_wih1, const float* __restrict__ e_whh1,
    const float* __restrict__ e_bih1, const float* __restrict__ e_bhh1,
    const float* __restrict__ d_wih0, const float* __restrict__ d_whh0,
    const float* __restrict__ d_bih0, const float* __restrict__ d_bhh0,
    const float* __restrict__ d_wih1, const float* __restrict__ d_whh1,
    const float* __restrict__ d_bih1, const float* __restrict__ d_bhh1,
    float* __restrict__ out,
    float* __restrict__ ys0, float* __restrict__ h1e,
    float* __restrict__ h0d, float* __restrict__ h1d,
    float* __restrict__ c0, float* __restrict__ c1,
    u64* __restrict__ packed, u32* __restrict__ bar) {
  __shared__ float smem[SMEM_FLOATS];
  const int tid = threadIdx.x;
  const int bid = blockIdx.x;
  const int gsz = gridDim.x;
  u32 ph = 0;

  const u64 tfb = decode_tfmask(tfm);

  // init: zero packed (agent: cross-block) and out row 0 (host-read only)
  for (int g = bid * 256 + tid; g < T * B * 8; g += gsz * 256) ast64(&packed[g], 0ull);
  for (int g = bid * 256 + tid; g < (B * V) / 8; g += gsz * 256) {
    float* p = out + (size_t)g * 8;
    *(float4*)p = make_float4(0.f, 0.f, 0.f, 0.f);
    *(float4*)(p + 4) = make_float4(0.f, 0.f, 0.f, 0.f);
  }
  gbar(bar, ++ph);

  // encoder: tick t = L0 step t || L1 step t-1 (software pipeline)
  for (int t = 0; t <= T; ++t) {
    if (t < T)
      for (int w = bid; w < 512; w += gsz)
        cell_run<E, 2>(w, t, emb_enc, src, tfb, nullptr,
                       e_wih0, e_whh0, e_bih0, e_bhh0,
                       ys0 + (size_t)((t + 1) & 1) * BH,
                       ys0 + (size_t)(t & 1) * BH, c0, smem, t == 0);
    if (t >= 1) {
      const int s = t - 1;
      for (int w = bid; w < 512; w += gsz)
        cell_run<H, 0>(w, s, ys0 + (size_t)(s & 1) * BH, src, tfb, nullptr,
                       e_wih1, e_whh1, e_bih1, e_bhh1,
                       h1e + (size_t)((s + 1) & 1) * BH,
                       h1e + (size_t)(s & 1) * BH, c1, smem, s == 0);
    }
    gbar(bar, ++ph);
  }

  // decoder
  for (int t = 1; t < T; ++t) {
    {
      const float* hp = (t == 1) ? (ys0 + (size_t)BH)
                                 : (h0d + (size_t)((t - 1) & 1) * BH);
      for (int w = bid; w < 512; w += gsz)
        cell_run<E, 1>(w, t, emb_dec, src, tfb, packed,
                       d_wih0, d_whh0, d_bih0, d_bhh0,
                       hp, h0d + (size_t)(t & 1) * BH, c0, smem, false);
    }
    gbar(bar, ++ph);
    {
      const float* hp = (t == 1) ? (h1e + (size_t)BH)
                                 : (h1d + (size_t)((t - 1) & 1) * BH);
      for (int w = bid; w < 512; w += gsz)
        cell_run<H, 0>(w, t, h0d + (size_t)(t & 1) * BH, src, tfb, nullptr,
                       d_wih1, d_whh1, d_bih1, d_bhh1,
                       hp, h1d + (size_t)(t & 1) * BH, c1, smem, false);
    }
    gbar(bar, ++ph);
    for (int w = bid; w < 500; w += gsz)
      fc_run(w, t, fc_w, fc_b, h1d + (size_t)(t & 1) * BH, out, packed, smem);
    gbar(bar, ++ph);
  }
}

// ---------------- fallback multi-kernel path (R2-equivalent, shared bodies) ----------------

__global__ __launch_bounds__(256) void k_init(u64* __restrict__ packed, float* __restrict__ out) {
  const int g = blockIdx.x * 256 + threadIdx.x;
  if (g < T * B * 8) ast64(&packed[g], 0ull);
  if (g < (B * V) / 8) {
    float* p = out + (size_t)g * 8;
    *(float4*)p = make_float4(0.f, 0.f, 0.f, 0.f);
    *(float4*)(p + 4) = make_float4(0.f, 0.f, 0.f, 0.f);
  }
}

__global__ __launch_bounds__(256, 2) void k_enc(
    int t, const int* __restrict__ src, const float* __restrict__ emb_enc,
    const float* __restrict__ e_wih0, const float* __restrict__ e_whh0,
    const float* __restrict__ e_bih0, const float* __restrict__ e_bhh0,
    const float* __restrict__ e_wih1, const float* __restrict__ e_whh1,
    const float* __restrict__ e_bih1, const float* __restrict__ e_bhh1,
    float* __restrict__ ys0, float* __restrict__ h1e,
    float* __restrict__ c0, float* __restrict__ c1) {
  __shared__ float smem[SMEM_FLOATS];
  const int w = blockIdx.x;
  if (w < 512) {
    if (t < T)
      cell_run<E, 2>(w, t, emb_enc, src, 0ull, nullptr,
                     e_wih0, e_whh0, e_bih0, e_bhh0,
                     ys0 + (size_t)((t + 1) & 1) * BH,
                     ys0 + (size_t)(t & 1) * BH, c0, smem, t == 0);
  } else {
    const int s = t - 1;
    if (s >= 0)
      cell_run<H, 0>(w - 512, s, ys0 + (size_t)(s & 1) * BH, src, 0ull, nullptr,
                     e_wih1, e_whh1, e_bih1, e_bhh1,
                     h1e + (size_t)((s + 1) & 1) * BH,
                     h1e + (size_t)(s & 1) * BH, c1, smem, s == 0);
  }
}

__global__ __launch_bounds__(256, 2) void k_deca(
    int t, const int* __restrict__ src, const unsigned char* __restrict__ tfm,
    const u64* __restrict__ packed, const float* __restrict__ emb_dec,
    const float* __restrict__ d_wih0, const float* __restrict__ d_whh0,
    const float* __restrict__ d_bih0, const float* __restrict__ d_bhh0,
    const float* __restrict__ ys0, float* __restrict__ h0d, float* __restrict__ c0) {
  __shared__ float smem[SMEM_FLOATS];
  const u64 tfb = decode_tfmask(tfm);
  const float* hp = (t == 1) ? (ys0 + (size_t)BH)
                             : (h0d + (size_t)((t - 1) & 1) * BH);
  cell_run<E, 1>(blockIdx.x, t, emb_dec, src, tfb, packed,
                 d_wih0, d_whh0, d_bih0, d_bhh0,
                 hp, h0d + (size_t)(t & 1) * BH, c0, smem, false);
}

__global__ __launch_bounds__(256, 2) void k_decb(
    int t, const float* __restrict__ d_wih1, const float* __restrict__ d_whh1,
    const float* __restrict__ d_bih1, const float* __restrict__ d_bhh1,
    const float* __restrict__ h0d, const float* __restrict__ h1e,
    float* __restrict__ h1d, float* __restrict__ c1) {
  __shared__ float smem[SMEM_FLOATS];
  const float* hp = (t == 1) ? (h1e + (size_t)BH)
                             : (h1d + (size_t)((t - 1) & 1) * BH);
  cell_run<H, 0>(blockIdx.x, t, h0d + (size_t)(t & 1) * BH, nullptr, 0ull, nullptr,
                 d_wih1, d_whh1, d_bih1, d_bhh1,
                 hp, h1d + (size_t)(t & 1) * BH, c1, smem, false);
}

__global__ __launch_bounds__(256, 2) void k_fc(
    int t, const float* __restrict__ fc_w, const float* __restrict__ fc_b,
    const float* __restrict__ h1d, float* __restrict__ out, u64* __restrict__ packed) {
  __shared__ float smem[SMEM_FLOATS];
  fc_run(blockIdx.x, t, fc_w, fc_b, h1d + (size_t)(t & 1) * BH, out, packed, smem);
}

// ---------------- host ----------------

extern "C" void kernel_launch(void* const* d_in, const int* in_sizes, int n_in,
                              void* d_out, int out_size, void* d_ws, size_t ws_size,
                              hipStream_t stream) {
  const int*           src     = (const int*)d_in[0];
  const unsigned char* tfm     = (const unsigned char*)d_in[1];
  const float* emb_enc = (const float*)d_in[2];
  const float* emb_dec = (const float*)d_in[3];
  const float* fc_w    = (const float*)d_in[4];
  const float* fc_b    = (const float*)d_in[5];
  const float* e_wih0  = (const float*)d_in[6];
  const float* e_whh0  = (const float*)d_in[7];
  const float* e_bih0  = (const float*)d_in[8];
  const float* e_bhh0  = (const float*)d_in[9];
  const float* e_wih1  = (const float*)d_in[10];
  const float* e_whh1  = (const float*)d_in[11];
  const float* e_bih1  = (const float*)d_in[12];
  const float* e_bhh1  = (const float*)d_in[13];
  const float* d_wih0  = (const float*)d_in[14];
  const float* d_whh0  = (const float*)d_in[15];
  const float* d_bih0  = (const float*)d_in[16];
  const float* d_bhh0  = (const float*)d_in[17];
  const float* d_wih1  = (const float*)d_in[18];
  const float* d_whh1  = (const float*)d_in[19];
  const float* d_bih1  = (const float*)d_in[20];
  const float* d_bhh1  = (const float*)d_in[21];

  float* out = (float*)d_out;
  float* wsf = (float*)d_ws;

  float* ys0 = wsf;                         // [2][B][H]
  float* h1e = ys0 + 2 * BH;                // [2][B][H]
  float* h0d = h1e + 2 * BH;                // [2][B][H]
  float* h1d = h0d + 2 * BH;                // [2][B][H]
  float* c0  = h1d + 2 * BH;                // [B][H]
  float* c1  = c0 + BH;                     // [B][H]
  u64*   packed = (u64*)(c1 + BH);          // [T][B][8]
  u32*   bar = (u32*)(packed + (size_t)T * B * 8);  // barrier counter (256B region)

  hipMemsetAsync(bar, 0, 256, stream);

  int dev = 0;
  (void)hipGetDevice(&dev);
  int ncu = 0;
  (void)hipDeviceGetAttribute(&ncu, hipDeviceAttributeMultiprocessorCount, dev);
  int occ = 0;
  hipError_t oe = hipOccupancyMaxActiveBlocksPerMultiprocessor(&occ, (const void*)mega, 256, 0);

  hipError_t le = hipErrorUnknown;
  if (oe == hipSuccess && occ > 0 && ncu > 0) {
    int gridN = occ * ncu;
    if (gridN > 512) gridN = 512;
    void* args[] = {
      (void*)&src, (void*)&tfm, (void*)&emb_enc, (void*)&emb_dec,
      (void*)&fc_w, (void*)&fc_b,
      (void*)&e_wih0, (void*)&e_whh0, (void*)&e_bih0, (void*)&e_bhh0,
      (void*)&e_wih1, (void*)&e_whh1, (void*)&e_bih1, (void*)&e_bhh1,
      (void*)&d_wih0, (void*)&d_whh0, (void*)&d_bih0, (void*)&d_bhh0,
      (void*)&d_wih1, (void*)&d_whh1, (void*)&d_bih1, (void*)&d_bhh1,
      (void*)&out, (void*)&ys0, (void*)&h1e, (void*)&h0d, (void*)&h1d,
      (void*)&c0, (void*)&c1, (void*)&packed, (void*)&bar
    };
    le = hipLaunchCooperativeKernel((void*)mega, dim3(gridN), dim3(256), args, 0, stream);
    if (le != hipSuccess && gridN > 256)
      le = hipLaunchCooperativeKernel((void*)mega, dim3(256), dim3(256), args, 0, stream);
  }

  if (le != hipSuccess) {
    // fallback: multi-kernel graph path
    k_init<<<512, 256, 0, stream>>>(packed, out);
    for (int t = 0; t <= T; ++t)
      k_enc<<<1024, 256, 0, stream>>>(t, src, emb_enc,
                                      e_wih0, e_whh0, e_bih0, e_bhh0,
                                      e_wih1, e_whh1, e_bih1, e_bhh1,
                                      ys0, h1e, c0, c1);
    for (int t = 1; t < T; ++t) {
      k_deca<<<512, 256, 0, stream>>>(t, src, tfm, packed, emb_dec,
                                      d_wih0, d_whh0, d_bih0, d_bhh0,
                                      ys0, h0d, c0);
      k_decb<<<512, 256, 0, stream>>>(t, d_wih1, d_whh1, d_bih1, d_bhh1,
                                      h0d, h1e, h1d, c1);
      k_fc<<<500, 256, 0, stream>>>(t, fc_w, fc_b, h1d, out, packed);
    }
  }
}

// Round 7
// 79543.378 us; speedup vs baseline: 1.0902x; 1.0902x over previous
//
#include <hip/hip_runtime.h>
#include <cstdint>

#define V 32000
#define E 128
#define H 1024
#define T 64
#define B 32
#define BH (B * H)

using u64 = unsigned long long;
using u32 = unsigned int;

__device__ __forceinline__ float sigm(float x) { return 1.f / (1.f + expf(-x)); }

// ================= cross-XCD transport (L1+L2 bypass, coalesced) =================
// 8 x 16B loads at 128B stride; early-clobber outputs so the address pair [a]
// can never be allocated into an output tuple (R6 crash root cause).
__device__ __forceinline__ void xload8_s128(float4 v[8], const float* base) {
  asm volatile(
      "global_load_dwordx4 %0, %[a], off sc0 sc1\n\t"
      "global_load_dwordx4 %1, %[a], off offset:128 sc0 sc1\n\t"
      "global_load_dwordx4 %2, %[a], off offset:256 sc0 sc1\n\t"
      "global_load_dwordx4 %3, %[a], off offset:384 sc0 sc1\n\t"
      "global_load_dwordx4 %4, %[a], off offset:512 sc0 sc1\n\t"
      "global_load_dwordx4 %5, %[a], off offset:640 sc0 sc1\n\t"
      "global_load_dwordx4 %6, %[a], off offset:768 sc0 sc1\n\t"
      "global_load_dwordx4 %7, %[a], off offset:896 sc0 sc1\n\t"
      "s_waitcnt vmcnt(0)"
      : "=&v"(v[0]), "=&v"(v[1]), "=&v"(v[2]), "=&v"(v[3]),
        "=&v"(v[4]), "=&v"(v[5]), "=&v"(v[6]), "=&v"(v[7])
      : [a] "v"(base)
      : "memory");
}
// 4 x 16B loads, contiguous 64B, single wait.
__device__ __forceinline__ void xload4_s16(float4 v[4], const float* base) {
  asm volatile(
      "global_load_dwordx4 %0, %[a], off sc0 sc1\n\t"
      "global_load_dwordx4 %1, %[a], off offset:16 sc0 sc1\n\t"
      "global_load_dwordx4 %2, %[a], off offset:32 sc0 sc1\n\t"
      "global_load_dwordx4 %3, %[a], off offset:48 sc0 sc1\n\t"
      "s_waitcnt vmcnt(0)"
      : "=&v"(v[0]), "=&v"(v[1]), "=&v"(v[2]), "=&v"(v[3])
      : [a] "v"(base)
      : "memory");
}
__device__ __forceinline__ void xstore(float* p, float v) {
  asm volatile("global_store_dword %0, %1, off sc0 sc1" :: "v"(p), "v"(v) : "memory");
}
__device__ __forceinline__ u64 ald64(const u64* p) {
  return __hip_atomic_load(p, __ATOMIC_RELAXED, __HIP_MEMORY_SCOPE_AGENT);
}
__device__ __forceinline__ void ast64(u64* p, u64 v) {
  __hip_atomic_store(p, v, __ATOMIC_RELAXED, __HIP_MEMORY_SCOPE_AGENT);
}

// tf_mask arrives as u8 bools or i32; i32 layout never has nonzero bytes at i%4!=0.
__device__ __forceinline__ u64 decode_tfmask(const unsigned char* __restrict__ raw) {
  int cnt = 0;
  for (int i = 0; i < 64; ++i)
    if ((i & 3) && raw[i]) cnt++;
  u64 bits = 0;
  if (cnt > 0) {
    for (int i = 0; i < 64; ++i) bits |= (u64)(raw[i] ? 1 : 0) << i;
  } else {
    const int* r = (const int*)raw;
    for (int i = 0; i < 64; ++i) bits |= (u64)(r[i] ? 1 : 0) << i;
  }
  return bits;
}

// ================= two-level grid barrier (monotonic counters) =================
// bar[g*32]     : group arrive counters (g = 0..7)
// bar[(8+g)*32] : group release epochs
// bar[16*32]    : global leader counter
__device__ __forceinline__ void gbar2(u32* bar, u32 ph, int bid, int gsz) {
  asm volatile("s_waitcnt vmcnt(0) lgkmcnt(0)" ::: "memory");
  __syncthreads();
  if (threadIdx.x == 0) {
    const int grp = bid & 7;
    const u32 gcnt = (u32)((gsz - grp + 7) >> 3);
    u32* garr = bar + grp * 32;
    u32* grel = bar + (8 + grp) * 32;
    u32* glob = bar + 16 * 32;
    u32 a = __hip_atomic_fetch_add(garr, 1u, __ATOMIC_RELAXED, __HIP_MEMORY_SCOPE_AGENT);
    if (a == ph * gcnt - 1u) {
      (void)__hip_atomic_fetch_add(glob, 1u, __ATOMIC_RELAXED, __HIP_MEMORY_SCOPE_AGENT);
      while (__hip_atomic_load(glob, __ATOMIC_RELAXED, __HIP_MEMORY_SCOPE_AGENT) < ph * 8u)
        __builtin_amdgcn_s_sleep(2);
      __hip_atomic_store(grel, ph, __ATOMIC_RELAXED, __HIP_MEMORY_SCOPE_AGENT);
    } else {
      while (__hip_atomic_load(grel, __ATOMIC_RELAXED, __HIP_MEMORY_SCOPE_AGENT) < ph)
        __builtin_amdgcn_s_sleep(8);
    }
  }
  __syncthreads();
}

// ================= LDS layout (floats) =================
#define ZS_STRIDE 260
#define SMEM_FLOATS (32 * ZS_STRIDE + 256 + 64)

// 4-gate partial dots over one staged chunk. wb = w + unit*WS + kc; gate stride H*WS.
template <int KC, int WS>
__device__ __forceinline__ void accum_chunk(const float* __restrict__ zs,
                                            const float* __restrict__ wb,
                                            int b, int kq, float acc[4]) {
  constexpr int KQ = KC / 4;
  const float* zrow = zs + b * ZS_STRIDE + kq * KQ;
  const float* wq = wb + kq * KQ;
  #pragma unroll
  for (int ks = 0; ks < KQ; ks += 16) {
    const float4 z0 = *(const float4*)(zrow + ks);
    const float4 z1 = *(const float4*)(zrow + ks + 4);
    const float4 z2 = *(const float4*)(zrow + ks + 8);
    const float4 z3 = *(const float4*)(zrow + ks + 12);
    #pragma unroll
    for (int g = 0; g < 4; ++g) {
      const float* wp = wq + (size_t)g * (size_t)H * WS + ks;
      const float4 w0 = *(const float4*)(wp);
      const float4 w1 = *(const float4*)(wp + 4);
      const float4 w2 = *(const float4*)(wp + 8);
      const float4 w3 = *(const float4*)(wp + 12);
      acc[g] += z0.x * w0.x + z0.y * w0.y + z0.z * w0.z + z0.w * w0.w
              + z1.x * w1.x + z1.y * w1.y + z1.z * w1.z + z1.w * w1.w
              + z2.x * w2.x + z2.y * w2.y + z2.z * w2.z + z2.w * w2.w
              + z3.x * w3.x + z3.y * w3.y + z3.z * w3.z + z3.w * w3.w;
    }
  }
}

// LSTM cell: 32 b x 4 kq x 2 units = 256 threads; unit = w*2 + u2.
// MODE 0: x = xsrc + bb*H (cross-XCD h -> xload); 1: x = emb_dec[tok(bb)] (cached);
// 2: x = emb_enc[src[t*B+bb]] (cached). first: skip phase H and c read.
template <int KX, int MODE>
__device__ void cell_run(
    int w, int t, const float* __restrict__ xsrc,
    const int* __restrict__ src, u64 tfb, const u64* __restrict__ packed,
    const float* __restrict__ wih, const float* __restrict__ whh,
    const float* __restrict__ bih, const float* __restrict__ bhh,
    const float* __restrict__ hprev, float* __restrict__ hout,
    float* __restrict__ cio, float* __restrict__ smem, bool first) {
  float* zs = smem;
  float* part = smem + 32 * ZS_STRIDE;
  int* toks = (int*)(smem + 32 * ZS_STRIDE + 256);

  const int tid = threadIdx.x;
  const int b = tid & 31;
  const int kq = (tid >> 5) & 3;
  const int u2 = tid >> 7;
  const int unit = w * 2 + u2;
  const int bb = tid >> 3, lq = tid & 7;

  if (MODE == 1) {
    if (tid < 32) {
      int tok;
      const int tm1 = t - 1;
      if (tm1 == 0) tok = src[tid];
      else if ((tfb >> tm1) & 1) tok = src[tm1 * B + tid];
      else {
        const u64* p = packed + ((size_t)tm1 * B + tid) * 8;
        u64 m = ald64(p);
        #pragma unroll
        for (int g = 1; g < 8; ++g) { u64 x = ald64(p + g); m = m > x ? m : x; }
        tok = (int)(0xFFFFFFFFu - (unsigned)(m & 0xFFFFFFFFull));
      }
      toks[tid] = tok;
    }
    __syncthreads();
  }

  float acc[4] = {0.f, 0.f, 0.f, 0.f};

  // ---- phase X ----
  if (MODE == 0) {
    const float* rowb = xsrc + (size_t)bb * H;       // KX == H
    #pragma unroll 1
    for (int kc = 0; kc < KX; kc += 256) {
      float4 vv[8];
      xload8_s128(vv, rowb + kc + 4 * lq);
      __builtin_amdgcn_sched_barrier(0);
      #pragma unroll
      for (int k = 0; k < 8; ++k)
        *(float4*)(zs + bb * ZS_STRIDE + 4 * (lq + 8 * k)) = vv[k];
      __syncthreads();
      accum_chunk<256, KX>(zs, wih + (size_t)unit * KX + kc, b, kq, acc);
      __syncthreads();
    }
  } else {
    const float* rowb = (MODE == 1) ? xsrc + (size_t)toks[bb] * E
                                    : xsrc + (size_t)src[t * B + bb] * E;
    #pragma unroll
    for (int j = lq; j < E / 4; j += 8)
      *(float4*)(zs + bb * ZS_STRIDE + 4 * j) = *(const float4*)(rowb + 4 * j);
    __syncthreads();
    accum_chunk<E, E>(zs, wih + (size_t)unit * E, b, kq, acc);
    __syncthreads();
  }

  // ---- phase H (skipped when hprev == 0) ----
  if (!first) {
    const float* rowb = hprev + (size_t)bb * H;
    #pragma unroll 1
    for (int kc = 0; kc < H; kc += 256) {
      float4 vv[8];
      xload8_s128(vv, rowb + kc + 4 * lq);
      __builtin_amdgcn_sched_barrier(0);
      #pragma unroll
      for (int k = 0; k < 8; ++k)
        *(float4*)(zs + bb * ZS_STRIDE + 4 * (lq + 8 * k)) = vv[k];
      __syncthreads();
      accum_chunk<256, H>(zs, whh + (size_t)unit * H + kc, b, kq, acc);
      __syncthreads();
    }
  }

  #pragma unroll
  for (int g = 0; g < 4; ++g) acc[g] += __shfl_xor(acc[g], 32);
  if (kq == 2)
    *(float4*)(part + (u2 * 32 + b) * 4) = make_float4(acc[0], acc[1], acc[2], acc[3]);
  __syncthreads();
  if (kq == 0) {
    const float4 p = *(const float4*)(part + (u2 * 32 + b) * 4);
    float gi = acc[0] + p.x + bih[unit]         + bhh[unit];
    float gf = acc[1] + p.y + bih[H + unit]     + bhh[H + unit];
    float gg = acc[2] + p.z + bih[2 * H + unit] + bhh[2 * H + unit];
    float go = acc[3] + p.w + bih[3 * H + unit] + bhh[3 * H + unit];
    float c = first ? 0.f : cio[b * H + unit];
    c = sigm(gf) * c + sigm(gi) * tanhf(gg);
    cio[b * H + unit] = c;                            // block-private: cached store
    xstore(&hout[b * H + unit], sigm(go) * tanhf(c)); // cross-XCD: bypass store
  }
  __syncthreads();
}

// ================= FC work unit w: v-range [w*64, w*64+64) =================

#define VPT 8
#define VB 64

__device__ void fc_run(int w, int t, const float* __restrict__ fc_w,
                       const float* __restrict__ fc_b, const float* __restrict__ h,
                       float* __restrict__ out, u64* __restrict__ packed,
                       float* __restrict__ smem) {
  float* hs = smem;                       // 32*132; later reused as out tile [32][68]
  u64* red = (u64*)(smem + 32 * 132);     // 8*32 u64
  const int tid = threadIdx.x;
  const int b = tid & 31;
  const int vl = tid >> 5;
  const int v0 = w * VB;

  float4 acc[VPT];
  #pragma unroll
  for (int q = 0; q < VPT; ++q) acc[q] = make_float4(0.f, 0.f, 0.f, 0.f);

  #pragma unroll 1
  for (int kc = 0; kc < H; kc += 128) {
    __syncthreads();
    {
      const int bb = tid >> 3;
      const int kk = (tid & 7) << 4;
      float4 vv[4];
      xload4_s16(vv, h + (size_t)bb * H + kc + kk);
      __builtin_amdgcn_sched_barrier(0);
      float* s = hs + bb * 132 + kk;
      *(float4*)(s) = vv[0]; *(float4*)(s + 4) = vv[1];
      *(float4*)(s + 8) = vv[2]; *(float4*)(s + 12) = vv[3];
    }
    __syncthreads();
    const float* hb = hs + b * 132;
    #pragma unroll
    for (int ks = 0; ks < 128; ks += 16) {
      const float4 x0 = *(const float4*)(hb + ks);
      const float4 x1 = *(const float4*)(hb + ks + 4);
      const float4 x2 = *(const float4*)(hb + ks + 8);
      const float4 x3 = *(const float4*)(hb + ks + 12);
      #pragma unroll
      for (int q = 0; q < VPT; ++q) {
        const float* wp = fc_w + (size_t)(v0 + (q << 3) + vl) * H + kc + ks;
        const float4 w0 = *(const float4*)(wp);
        const float4 w1 = *(const float4*)(wp + 4);
        const float4 w2 = *(const float4*)(wp + 8);
        const float4 w3 = *(const float4*)(wp + 12);
        acc[q].x += x0.x * w0.x; acc[q].y += x0.y * w0.y; acc[q].z += x0.z * w0.z; acc[q].w += x0.w * w0.w;
        acc[q].x += x1.x * w1.x; acc[q].y += x1.y * w1.y; acc[q].z += x1.z * w1.z; acc[q].w += x1.w * w1.w;
        acc[q].x += x2.x * w2.x; acc[q].y += x2.y * w2.y; acc[q].z += x2.z * w2.z; acc[q].w += x2.w * w2.w;
        acc[q].x += x3.x * w3.x; acc[q].y += x3.y * w3.y; acc[q].z += x3.z * w3.z; acc[q].w += x3.w * w3.w;
      }
    }
  }

  u64 best = 0ull;
  float vals[VPT];
  #pragma unroll
  for (int q = 0; q < VPT; ++q) {
    const int v = v0 + (q << 3) + vl;
    float val = ((acc[q].x + acc[q].y) + (acc[q].z + acc[q].w)) + fc_b[v];
    vals[q] = val;
    unsigned uu = __float_as_uint(val);
    uu = (uu & 0x80000000u) ? ~uu : (uu | 0x80000000u);
    u64 pk = ((u64)uu << 32) | (u64)(0xFFFFFFFFu - (unsigned)v);  // ties -> smallest v
    best = best > pk ? best : pk;
  }
  red[vl * 32 + b] = best;
  __syncthreads();

  float* tile = hs;                        // [32][68]
  #pragma unroll
  for (int q = 0; q < VPT; ++q) tile[b * 68 + (q << 3) + vl] = vals[q];

  if (tid < 32) {
    u64 m = red[tid];
    #pragma unroll
    for (int q = 1; q < 8; ++q) { u64 x = red[q * 32 + tid]; m = m > x ? m : x; }
    atomicMax(&packed[((size_t)t * B + tid) * 8 + (w & 7)], m);  // device scope
  }
  __syncthreads();
  {
    const int bb = tid >> 3, j = tid & 7;
    const float4 o0 = *(const float4*)(tile + bb * 68 + j * 8);
    const float4 o1 = *(const float4*)(tile + bb * 68 + j * 8 + 4);
    float* op = out + (size_t)t * (B * V) + (size_t)bb * V + v0 + j * 8;
    *(float4*)op = o0;
    *(float4*)(op + 4) = o1;
  }
  __syncthreads();
}

// ================= persistent cooperative mega-kernel =================

__global__ __launch_bounds__(256, 2) void mega(
    const int* __restrict__ src, const unsigned char* __restrict__ tfm,
    const float* __restrict__ emb_enc, const float* __restrict__ emb_dec,
    const float* __restrict__ fc_w, const float* __restrict__ fc_b,
    const float* __restrict__ e_wih0, const float* __restrict__ e_whh0,
    const float* __restrict__ e_bih0, const float* __restrict__ e_bhh0,
    const float* __restrict__ e_wih1, const float* __restrict__ e_whh1,
    const float* __restrict__ e_bih1, const float* __restrict__ e_bhh1,
    const float* __restrict__ d_wih0, const float* __restrict__ d_whh0,
    const float* __restrict__ d_bih0, const float* __restrict__ d_bhh0,
    const float* __restrict__ d_wih1, const float* __restrict__ d_whh1,
    const float* __restrict__ d_bih1, const float* __restrict__ d_bhh1,
    float* __restrict__ out,
    float* __restrict__ ys0, float* __restrict__ h1e,
    float* __restrict__ h0d, float* __restrict__ h1d,
    float* __restrict__ c0, float* __restrict__ c1,
    u64* __restrict__ packed, u32* __restrict__ bar) {
  __shared__ float smem[SMEM_FLOATS];
  const int tid = threadIdx.x;
  const int bid = blockIdx.x;
  const int gsz = gridDim.x;
  u32 ph = 0;

  const u64 tfb = decode_tfmask(tfm);

  // init: zero packed (cross-block) and out row 0 (host-read)
  for (int g = bid * 256 + tid; g < T * B * 8; g += gsz * 256) ast64(&packed[g], 0ull);
  for (int g = bid * 256 + tid; g < (B * V) / 8; g += gsz * 256) {
    float* p = out + (size_t)g * 8;
    *(float4*)p = make_float4(0.f, 0.f, 0.f, 0.f);
    *(float4*)(p + 4) = make_float4(0.f, 0.f, 0.f, 0.f);
  }
  gbar2(bar, ++ph, bid, gsz);

  // encoder: tick t = L0 step t || L1 step t-1 (software pipeline)
  for (int t = 0; t <= T; ++t) {
    if (t < T)
      for (int w = bid; w < 512; w += gsz)
        cell_run<E, 2>(w, t, emb_enc, src, tfb, nullptr,
                       e_wih0, e_whh0, e_bih0, e_bhh0,
                       ys0 + (size_t)((t + 1) & 1) * BH,
                       ys0 + (size_t)(t & 1) * BH, c0, smem, t == 0);
    if (t >= 1) {
      const int s = t - 1;
      for (int w = bid; w < 512; w += gsz)
        cell_run<H, 0>(w, s, ys0 + (size_t)(s & 1) * BH, src, tfb, nullptr,
                       e_wih1, e_whh1, e_bih1, e_bhh1,
                       h1e + (size_t)((s + 1) & 1) * BH,
                       h1e + (size_t)(s & 1) * BH, c1, smem, s == 0);
    }
    gbar2(bar, ++ph, bid, gsz);
  }

  // decoder
  for (int t = 1; t < T; ++t) {
    {
      const float* hp = (t == 1) ? (ys0 + (size_t)BH)
                                 : (h0d + (size_t)((t - 1) & 1) * BH);
      for (int w = bid; w < 512; w += gsz)
        cell_run<E, 1>(w, t, emb_dec, src, tfb, packed,
                       d_wih0, d_whh0, d_bih0, d_bhh0,
                       hp, h0d + (size_t)(t & 1) * BH, c0, smem, false);
    }
    gbar2(bar, ++ph, bid, gsz);
    {
      const float* hp = (t == 1) ? (h1e + (size_t)BH)
                                 : (h1d + (size_t)((t - 1) & 1) * BH);
      for (int w = bid; w < 512; w += gsz)
        cell_run<H, 0>(w, t, h0d + (size_t)(t & 1) * BH, src, tfb, nullptr,
                       d_wih1, d_whh1, d_bih1, d_bhh1,
                       hp, h1d + (size_t)(t & 1) * BH, c1, smem, false);
    }
    gbar2(bar, ++ph, bid, gsz);
    for (int w = bid; w < 500; w += gsz)
      fc_run(w, t, fc_w, fc_b, h1d + (size_t)(t & 1) * BH, out, packed, smem);
    gbar2(bar, ++ph, bid, gsz);
  }
}

// ================= fallback multi-kernel path =================

__global__ __launch_bounds__(256) void k_init(u64* __restrict__ packed, float* __restrict__ out) {
  const int g = blockIdx.x * 256 + threadIdx.x;
  if (g < T * B * 8) ast64(&packed[g], 0ull);
  if (g < (B * V) / 8) {
    float* p = out + (size_t)g * 8;
    *(float4*)p = make_float4(0.f, 0.f, 0.f, 0.f);
    *(float4*)(p + 4) = make_float4(0.f, 0.f, 0.f, 0.f);
  }
}

__global__ __launch_bounds__(256, 2) void k_enc(
    int t, const int* __restrict__ src, const float* __restrict__ emb_enc,
    const float* __restrict__ e_wih0, const float* __restrict__ e_whh0,
    const float* __restrict__ e_bih0, const float* __restrict__ e_bhh0,
    const float* __restrict__ e_wih1, const float* __restrict__ e_whh1,
    const float* __restrict__ e_bih1, const float* __restrict__ e_bhh1,
    float* __restrict__ ys0, float* __restrict__ h1e,
    float* __restrict__ c0, float* __restrict__ c1) {
  __shared__ float smem[SMEM_FLOATS];
  const int w = blockIdx.x;
  if (w < 512) {
    if (t < T)
      cell_run<E, 2>(w, t, emb_enc, src, 0ull, nullptr,
                     e_wih0, e_whh0, e_bih0, e_bhh0,
                     ys0 + (size_t)((t + 1) & 1) * BH,
                     ys0 + (size_t)(t & 1) * BH, c0, smem, t == 0);
  } else {
    const int s = t - 1;
    if (s >= 0)
      cell_run<H, 0>(w - 512, s, ys0 + (size_t)(s & 1) * BH, src, 0ull, nullptr,
                     e_wih1, e_whh1, e_bih1, e_bhh1,
                     h1e + (size_t)((s + 1) & 1) * BH,
                     h1e + (size_t)(s & 1) * BH, c1, smem, s == 0);
  }
}

__global__ __launch_bounds__(256, 2) void k_deca(
    int t, const int* __restrict__ src, const unsigned char* __restrict__ tfm,
    const u64* __restrict__ packed, const float* __restrict__ emb_dec,
    const float* __restrict__ d_wih0, const float* __restrict__ d_whh0,
    const float* __restrict__ d_bih0, const float* __restrict__ d_bhh0,
    const float* __restrict__ ys0, float* __restrict__ h0d, float* __restrict__ c0) {
  __shared__ float smem[SMEM_FLOATS];
  const u64 tfb = decode_tfmask(tfm);
  const float* hp = (t == 1) ? (ys0 + (size_t)BH)
                             : (h0d + (size_t)((t - 1) & 1) * BH);
  cell_run<E, 1>(blockIdx.x, t, emb_dec, src, tfb, packed,
                 d_wih0, d_whh0, d_bih0, d_bhh0,
                 hp, h0d + (size_t)(t & 1) * BH, c0, smem, false);
}

__global__ __launch_bounds__(256, 2) void k_decb(
    int t, const float* __restrict__ d_wih1, const float* __restrict__ d_whh1,
    const float* __restrict__ d_bih1, const float* __restrict__ d_bhh1,
    const float* __restrict__ h0d, const float* __restrict__ h1e,
    float* __restrict__ h1d, float* __restrict__ c1) {
  __shared__ float smem[SMEM_FLOATS];
  const float* hp = (t == 1) ? (h1e + (size_t)BH)
                             : (h1d + (size_t)((t - 1) & 1) * BH);
  cell_run<H, 0>(blockIdx.x, t, h0d + (size_t)(t & 1) * BH, nullptr, 0ull, nullptr,
                 d_wih1, d_whh1, d_bih1, d_bhh1,
                 hp, h1d + (size_t)(t & 1) * BH, c1, smem, false);
}

__global__ __launch_bounds__(256, 2) void k_fc(
    int t, const float* __restrict__ fc_w, const float* __restrict__ fc_b,
    const float* __restrict__ h1d, float* __restrict__ out, u64* __restrict__ packed) {
  __shared__ float smem[SMEM_FLOATS];
  fc_run(blockIdx.x, t, fc_w, fc_b, h1d + (size_t)(t & 1) * BH, out, packed, smem);
}

// ================= host =================

extern "C" void kernel_launch(void* const* d_in, const int* in_sizes, int n_in,
                              void* d_out, int out_size, void* d_ws, size_t ws_size,
                              hipStream_t stream) {
  const int*           src     = (const int*)d_in[0];
  const unsigned char* tfm     = (const unsigned char*)d_in[1];
  const float* emb_enc = (const float*)d_in[2];
  const float* emb_dec = (const float*)d_in[3];
  const float* fc_w    = (const float*)d_in[4];
  const float* fc_b    = (const float*)d_in[5];
  const float* e_wih0  = (const float*)d_in[6];
  const float* e_whh0  = (const float*)d_in[7];
  const float* e_bih0  = (const float*)d_in[8];
  const float* e_bhh0  = (const float*)d_in[9];
  const float* e_wih1  = (const float*)d_in[10];
  const float* e_whh1  = (const float*)d_in[11];
  const float* e_bih1  = (const float*)d_in[12];
  const float* e_bhh1  = (const float*)d_in[13];
  const float* d_wih0  = (const float*)d_in[14];
  const float* d_whh0  = (const float*)d_in[15];
  const float* d_bih0  = (const float*)d_in[16];
  const float* d_bhh0  = (const float*)d_in[17];
  const float* d_wih1  = (const float*)d_in[18];
  const float* d_whh1  = (const float*)d_in[19];
  const float* d_bih1  = (const float*)d_in[20];
  const float* d_bhh1  = (const float*)d_in[21];

  float* out = (float*)d_out;
  float* wsf = (float*)d_ws;

  float* ys0 = wsf;                         // [2][B][H]
  float* h1e = ys0 + 2 * BH;                // [2][B][H]
  float* h0d = h1e + 2 * BH;                // [2][B][H]
  float* h1d = h0d + 2 * BH;                // [2][B][H]
  float* c0  = h1d + 2 * BH;                // [B][H]
  float* c1  = c0 + BH;                     // [B][H]
  u64*   packed = (u64*)(c1 + BH);          // [T][B][8]
  u32*   bar = (u32*)(packed + (size_t)T * B * 8);  // barrier region (17 lines)

  hipMemsetAsync(bar, 0, 4096, stream);

  int dev = 0;
  (void)hipGetDevice(&dev);
  int ncu = 0;
  (void)hipDeviceGetAttribute(&ncu, hipDeviceAttributeMultiprocessorCount, dev);
  int occ = 0;
  hipError_t oe = hipOccupancyMaxActiveBlocksPerMultiprocessor(&occ, (const void*)mega, 256, 0);

  hipError_t le = hipErrorUnknown;
  if (oe == hipSuccess && occ > 0 && ncu > 0) {
    int gridN = occ * ncu;
    if (gridN > 512) gridN = 512;
    void* args[] = {
      (void*)&src, (void*)&tfm, (void*)&emb_enc, (void*)&emb_dec,
      (void*)&fc_w, (void*)&fc_b,
      (void*)&e_wih0, (void*)&e_whh0, (void*)&e_bih0, (void*)&e_bhh0,
      (void*)&e_wih1, (void*)&e_whh1, (void*)&e_bih1, (void*)&e_bhh1,
      (void*)&d_wih0, (void*)&d_whh0, (void*)&d_bih0, (void*)&d_bhh0,
      (void*)&d_wih1, (void*)&d_whh1, (void*)&d_bih1, (void*)&d_bhh1,
      (void*)&out, (void*)&ys0, (void*)&h1e, (void*)&h0d, (void*)&h1d,
      (void*)&c0, (void*)&c1, (void*)&packed, (void*)&bar
    };
    le = hipLaunchCooperativeKernel((void*)mega, dim3(gridN), dim3(256), args, 0, stream);
    if (le != hipSuccess && gridN > 256)
      le = hipLaunchCooperativeKernel((void*)mega, dim3(256), dim3(256), args, 0, stream);
  }

  if (le != hipSuccess) {
    // fallback: multi-kernel graph path
    k_init<<<512, 256, 0, stream>>>(packed, out);
    for (int t = 0; t <= T; ++t)
      k_enc<<<1024, 256, 0, stream>>>(t, src, emb_enc,
                                      e_wih0, e_whh0, e_bih0, e_bhh0,
                                      e_wih1, e_whh1, e_bih1, e_bhh1,
                                      ys0, h1e, c0, c1);
    for (int t = 1; t < T; ++t) {
      k_deca<<<512, 256, 0, stream>>>(t, src, tfm, packed, emb_dec,
                                      d_wih0, d_whh0, d_bih0, d_bhh0,
                                      ys0, h0d, c0);
      k_decb<<<512, 256, 0, stream>>>(t, d_wih1, d_whh1, d_bih1, d_bhh1,
                                      h0d, h1e, h1d, c1);
      k_fc<<<500, 256, 0, stream>>>(t, fc_w, fc_b, h1d, out, packed);
    }
  }
}

// Round 10
// 64194.733 us; speedup vs baseline: 1.3509x; 1.2391x over previous
//
#include <hip/hip_runtime.h>
#include <cstdint>

#define V 32000
#define E 128
#define H 1024
#define T 64
#define B 32
#define BH (B * H)

using u64 = unsigned long long;
using u32 = unsigned int;
typedef float vf4 __attribute__((ext_vector_type(4)));   // native clang vector for builtins

__device__ __forceinline__ float sigm(float x) { return 1.f / (1.f + expf(-x)); }

// tf_mask arrives as u8 bools or i32; i32 layout never has nonzero bytes at i%4!=0.
__device__ __forceinline__ u64 decode_tfmask(const unsigned char* __restrict__ raw) {
  int cnt = 0;
  for (int i = 0; i < 64; ++i)
    if ((i & 3) && raw[i]) cnt++;
  u64 bits = 0;
  if (cnt > 0) {
    for (int i = 0; i < 64; ++i) bits |= (u64)(raw[i] ? 1 : 0) << i;
  } else {
    const int* r = (const int*)raw;
    for (int i = 0; i < 64; ++i) bits |= (u64)(r[i] ? 1 : 0) << i;
  }
  return bits;
}

// non-temporal 16B store (keeps the 262MB out-stream from evicting fc_w out of L3).
// R9 lesson: the builtin needs a native clang vector type, not HIP's float4 class.
__device__ __forceinline__ void nt_store4(float* p, float4 v) {
  vf4 w; w.x = v.x; w.y = v.y; w.z = v.z; w.w = v.w;
  __builtin_nontemporal_store(w, (vf4*)p);
}

// ================= LDS layout (floats) =================
#define ZS_STRIDE 260
#define SMEM_FLOATS (32 * ZS_STRIDE + 256 + 64)

// 4-gate partial dots over one staged chunk. wb = w + unit*WS + kc; gate stride H*WS.
template <int KC, int WS>
__device__ __forceinline__ void accum_chunk(const float* __restrict__ zs,
                                            const float* __restrict__ wb,
                                            int b, int kq, float acc[4]) {
  constexpr int KQ = KC / 4;
  const float* zrow = zs + b * ZS_STRIDE + kq * KQ;
  const float* wq = wb + kq * KQ;
  #pragma unroll
  for (int ks = 0; ks < KQ; ks += 16) {
    const float4 z0 = *(const float4*)(zrow + ks);
    const float4 z1 = *(const float4*)(zrow + ks + 4);
    const float4 z2 = *(const float4*)(zrow + ks + 8);
    const float4 z3 = *(const float4*)(zrow + ks + 12);
    #pragma unroll
    for (int g = 0; g < 4; ++g) {
      const float* wp = wq + (size_t)g * (size_t)H * WS + ks;
      const float4 w0 = *(const float4*)(wp);
      const float4 w1 = *(const float4*)(wp + 4);
      const float4 w2 = *(const float4*)(wp + 8);
      const float4 w3 = *(const float4*)(wp + 12);
      acc[g] += z0.x * w0.x + z0.y * w0.y + z0.z * w0.z + z0.w * w0.w
              + z1.x * w1.x + z1.y * w1.y + z1.z * w1.z + z1.w * w1.w
              + z2.x * w2.x + z2.y * w2.y + z2.z * w2.z + z2.w * w2.w
              + z3.x * w3.x + z3.y * w3.y + z3.z * w3.z + z3.w * w3.w;
    }
  }
}

// LSTM cell: 32 b x 4 kq x 2 units = 256 threads; unit = w*2 + u2.
// MODE 0: x = xsrc + bb*H; 1: x = emb_dec[tok(bb)]; 2: x = emb_enc[src[t*B+bb]].
// first: hprev == 0 (skip phase H) and c == 0 (skip c read).
template <int KX, int MODE>
__device__ void cell_run(
    int w, int t, const float* __restrict__ xsrc,
    const int* __restrict__ src, u64 tfb, const u64* __restrict__ packed,
    const float* __restrict__ wih, const float* __restrict__ whh,
    const float* __restrict__ bih, const float* __restrict__ bhh,
    const float* __restrict__ hprev, float* __restrict__ hout,
    float* __restrict__ cio, float* __restrict__ smem, bool first) {
  float* zs = smem;
  float* part = smem + 32 * ZS_STRIDE;
  int* toks = (int*)(smem + 32 * ZS_STRIDE + 256);

  const int tid = threadIdx.x;
  const int b = tid & 31;
  const int kq = (tid >> 5) & 3;
  const int u2 = tid >> 7;
  const int unit = w * 2 + u2;
  const int bb = tid >> 3, lq = tid & 7;

  if (MODE == 1) {
    if (tid < 32) {
      int tok;
      const int tm1 = t - 1;
      if (tm1 == 0) tok = src[tid];
      else if ((tfb >> tm1) & 1) tok = src[tm1 * B + tid];
      else {
        const u64* p = packed + ((size_t)tm1 * B + tid) * 8;
        u64 m = p[0];
        #pragma unroll
        for (int g = 1; g < 8; ++g) { u64 x = p[g]; m = m > x ? m : x; }
        tok = (int)(0xFFFFFFFFu - (unsigned)(m & 0xFFFFFFFFull));
      }
      toks[tid] = tok;
    }
    __syncthreads();
  }

  float acc[4] = {0.f, 0.f, 0.f, 0.f};

  // ---- phase X ----
  if (MODE == 0) {
    const float* rowb = xsrc + (size_t)bb * H;       // KX == H
    #pragma unroll 1
    for (int kc = 0; kc < KX; kc += 256) {
      #pragma unroll
      for (int j = lq; j < 64; j += 8)
        *(float4*)(zs + bb * ZS_STRIDE + 4 * j) = *(const float4*)(rowb + kc + 4 * j);
      __syncthreads();
      accum_chunk<256, KX>(zs, wih + (size_t)unit * KX + kc, b, kq, acc);
      __syncthreads();
    }
  } else {
    const float* rowb = (MODE == 1) ? xsrc + (size_t)toks[bb] * E
                                    : xsrc + (size_t)src[t * B + bb] * E;
    #pragma unroll
    for (int j = lq; j < E / 4; j += 8)
      *(float4*)(zs + bb * ZS_STRIDE + 4 * j) = *(const float4*)(rowb + 4 * j);
    __syncthreads();
    accum_chunk<E, E>(zs, wih + (size_t)unit * E, b, kq, acc);
    __syncthreads();
  }

  // ---- phase H (skipped when hprev == 0) ----
  if (!first) {
    const float* rowb = hprev + (size_t)bb * H;
    #pragma unroll 1
    for (int kc = 0; kc < H; kc += 256) {
      #pragma unroll
      for (int j = lq; j < 64; j += 8)
        *(float4*)(zs + bb * ZS_STRIDE + 4 * j) = *(const float4*)(rowb + kc + 4 * j);
      __syncthreads();
      accum_chunk<256, H>(zs, whh + (size_t)unit * H + kc, b, kq, acc);
      __syncthreads();
    }
  }

  #pragma unroll
  for (int g = 0; g < 4; ++g) acc[g] += __shfl_xor(acc[g], 32);
  if (kq == 2)
    *(float4*)(part + (u2 * 32 + b) * 4) = make_float4(acc[0], acc[1], acc[2], acc[3]);
  __syncthreads();
  if (kq == 0) {
    const float4 p = *(const float4*)(part + (u2 * 32 + b) * 4);
    float gi = acc[0] + p.x + bih[unit]         + bhh[unit];
    float gf = acc[1] + p.y + bih[H + unit]     + bhh[H + unit];
    float gg = acc[2] + p.z + bih[2 * H + unit] + bhh[2 * H + unit];
    float go = acc[3] + p.w + bih[3 * H + unit] + bhh[3 * H + unit];
    float c = first ? 0.f : cio[b * H + unit];
    c = sigm(gf) * c + sigm(gi) * tanhf(gg);
    cio[b * H + unit] = c;
    hout[b * H + unit] = sigm(go) * tanhf(c);
  }
}

// ================= FC work unit w: v-range [w*64, w*64+64) =================

#define VPT 8
#define VB 64

__device__ void fc_run(int w, int t, const float* __restrict__ fc_w,
                       const float* __restrict__ fc_b, const float* __restrict__ h,
                       float* __restrict__ out, u64* __restrict__ packed,
                       float* __restrict__ smem) {
  float* hs = smem;                       // 32*132; later reused as out tile [32][68]
  u64* red = (u64*)(smem + 32 * 132);     // 8*32 u64
  const int tid = threadIdx.x;
  const int b = tid & 31;
  const int vl = tid >> 5;
  const int v0 = w * VB;

  float4 acc[VPT];
  #pragma unroll
  for (int q = 0; q < VPT; ++q) acc[q] = make_float4(0.f, 0.f, 0.f, 0.f);

  #pragma unroll 1
  for (int kc = 0; kc < H; kc += 128) {
    __syncthreads();
    {
      const int bb = tid >> 3;
      const int kk = (tid & 7) << 4;
      const float* gp = h + (size_t)bb * H + kc + kk;
      float4 x0 = *(const float4*)(gp);
      float4 x1 = *(const float4*)(gp + 4);
      float4 x2 = *(const float4*)(gp + 8);
      float4 x3 = *(const float4*)(gp + 12);
      float* s = hs + bb * 132 + kk;
      *(float4*)(s) = x0; *(float4*)(s + 4) = x1;
      *(float4*)(s + 8) = x2; *(float4*)(s + 12) = x3;
    }
    __syncthreads();
    const float* hb = hs + b * 132;
    #pragma unroll
    for (int ks = 0; ks < 128; ks += 16) {
      const float4 x0 = *(const float4*)(hb + ks);
      const float4 x1 = *(const float4*)(hb + ks + 4);
      const float4 x2 = *(const float4*)(hb + ks + 8);
      const float4 x3 = *(const float4*)(hb + ks + 12);
      #pragma unroll
      for (int q = 0; q < VPT; ++q) {
        const float* wp = fc_w + (size_t)(v0 + (q << 3) + vl) * H + kc + ks;
        const float4 w0 = *(const float4*)(wp);
        const float4 w1 = *(const float4*)(wp + 4);
        const float4 w2 = *(const float4*)(wp + 8);
        const float4 w3 = *(const float4*)(wp + 12);
        acc[q].x += x0.x * w0.x; acc[q].y += x0.y * w0.y; acc[q].z += x0.z * w0.z; acc[q].w += x0.w * w0.w;
        acc[q].x += x1.x * w1.x; acc[q].y += x1.y * w1.y; acc[q].z += x1.z * w1.z; acc[q].w += x1.w * w1.w;
        acc[q].x += x2.x * w2.x; acc[q].y += x2.y * w2.y; acc[q].z += x2.z * w2.z; acc[q].w += x2.w * w2.w;
        acc[q].x += x3.x * w3.x; acc[q].y += x3.y * w3.y; acc[q].z += x3.z * w3.z; acc[q].w += x3.w * w3.w;
      }
    }
  }

  u64 best = 0ull;
  float vals[VPT];
  #pragma unroll
  for (int q = 0; q < VPT; ++q) {
    const int v = v0 + (q << 3) + vl;
    float val = ((acc[q].x + acc[q].y) + (acc[q].z + acc[q].w)) + fc_b[v];
    vals[q] = val;
    unsigned uu = __float_as_uint(val);
    uu = (uu & 0x80000000u) ? ~uu : (uu | 0x80000000u);
    u64 pk = ((u64)uu << 32) | (u64)(0xFFFFFFFFu - (unsigned)v);  // ties -> smallest v
    best = best > pk ? best : pk;
  }
  red[vl * 32 + b] = best;
  __syncthreads();

  float* tile = hs;                        // [32][68]
  #pragma unroll
  for (int q = 0; q < VPT; ++q) tile[b * 68 + (q << 3) + vl] = vals[q];

  if (tid < 32) {
    u64 m = red[tid];
    #pragma unroll
    for (int q = 1; q < 8; ++q) { u64 x = red[q * 32 + tid]; m = m > x ? m : x; }
    atomicMax(&packed[((size_t)t * B + tid) * 8 + (w & 7)], m);  // device scope
  }
  __syncthreads();
  {
    const int bb = tid >> 3, j = tid & 7;
    const float4 o0 = *(const float4*)(tile + bb * 68 + j * 8);
    const float4 o1 = *(const float4*)(tile + bb * 68 + j * 8 + 4);
    float* op = out + (size_t)t * (B * V) + (size_t)bb * V + v0 + j * 8;
    nt_store4(op, o0);
    nt_store4(op + 4, o1);
  }
}

// ================= kernels =================

__global__ __launch_bounds__(256) void ki(u64* __restrict__ packed, float* __restrict__ out) {
  const int g = blockIdx.x * 256 + threadIdx.x;
  if (g < T * B * 8) packed[g] = 0ull;
  if (g < (B * V) / 8) {
    float* p = out + (size_t)g * 8;
    nt_store4(p, make_float4(0.f, 0.f, 0.f, 0.f));
    nt_store4(p + 4, make_float4(0.f, 0.f, 0.f, 0.f));
  }
}

__global__ __launch_bounds__(256, 2) void ke(
    int t, const int* __restrict__ src, const float* __restrict__ emb_enc,
    const float* __restrict__ e_wih0, const float* __restrict__ e_whh0,
    const float* __restrict__ e_bih0, const float* __restrict__ e_bhh0,
    const float* __restrict__ e_wih1, const float* __restrict__ e_whh1,
    const float* __restrict__ e_bih1, const float* __restrict__ e_bhh1,
    float* __restrict__ ys0, float* __restrict__ h1e,
    float* __restrict__ c0, float* __restrict__ c1) {
  __shared__ float smem[SMEM_FLOATS];
  const int w = blockIdx.x;
  if (w < 512) {
    if (t < T)
      cell_run<E, 2>(w, t, emb_enc, src, 0ull, nullptr,
                     e_wih0, e_whh0, e_bih0, e_bhh0,
                     ys0 + (size_t)((t + 1) & 1) * BH,
                     ys0 + (size_t)(t & 1) * BH, c0, smem, t == 0);
  } else {
    const int s = t - 1;
    if (s >= 0)
      cell_run<H, 0>(w - 512, s, ys0 + (size_t)(s & 1) * BH, src, 0ull, nullptr,
                     e_wih1, e_whh1, e_bih1, e_bhh1,
                     h1e + (size_t)((s + 1) & 1) * BH,
                     h1e + (size_t)(s & 1) * BH, c1, smem, s == 0);
  }
}

__global__ __launch_bounds__(256, 2) void ka(
    int t, const int* __restrict__ src, const unsigned char* __restrict__ tfm,
    const u64* __restrict__ packed, const float* __restrict__ emb_dec,
    const float* __restrict__ d_wih0, const float* __restrict__ d_whh0,
    const float* __restrict__ d_bih0, const float* __restrict__ d_bhh0,
    const float* __restrict__ ys0, float* __restrict__ h0d, float* __restrict__ c0) {
  __shared__ float smem[SMEM_FLOATS];
  const u64 tfb = decode_tfmask(tfm);
  const float* hp = (t == 1) ? (ys0 + (size_t)BH)
                             : (h0d + (size_t)((t - 1) & 1) * BH);
  cell_run<E, 1>(blockIdx.x, t, emb_dec, src, tfb, packed,
                 d_wih0, d_whh0, d_bih0, d_bhh0,
                 hp, h0d + (size_t)(t & 1) * BH, c0, smem, false);
}

__global__ __launch_bounds__(256, 2) void kb(
    int t, const float* __restrict__ d_wih1, const float* __restrict__ d_whh1,
    const float* __restrict__ d_bih1, const float* __restrict__ d_bhh1,
    const float* __restrict__ h0d, const float* __restrict__ h1e,
    float* __restrict__ h1d, float* __restrict__ c1) {
  __shared__ float smem[SMEM_FLOATS];
  const float* hp = (t == 1) ? (h1e + (size_t)BH)
                             : (h1d + (size_t)((t - 1) & 1) * BH);
  cell_run<H, 0>(blockIdx.x, t, h0d + (size_t)(t & 1) * BH, nullptr, 0ull, nullptr,
                 d_wih1, d_whh1, d_bih1, d_bhh1,
                 hp, h1d + (size_t)(t & 1) * BH, c1, smem, false);
}

__global__ __launch_bounds__(256, 2) void kf(
    int t, const float* __restrict__ fc_w, const float* __restrict__ fc_b,
    const float* __restrict__ h1d, float* __restrict__ out, u64* __restrict__ packed) {
  __shared__ float smem[SMEM_FLOATS];
  fc_run(blockIdx.x, t, fc_w, fc_b, h1d + (size_t)(t & 1) * BH, out, packed, smem);
}

// ================= host =================

extern "C" void kernel_launch(void* const* d_in, const int* in_sizes, int n_in,
                              void* d_out, int out_size, void* d_ws, size_t ws_size,
                              hipStream_t stream) {
  const int*           src     = (const int*)d_in[0];
  const unsigned char* tfm     = (const unsigned char*)d_in[1];
  const float* emb_enc = (const float*)d_in[2];
  const float* emb_dec = (const float*)d_in[3];
  const float* fc_w    = (const float*)d_in[4];
  const float* fc_b    = (const float*)d_in[5];
  const float* e_wih0  = (const float*)d_in[6];
  const float* e_whh0  = (const float*)d_in[7];
  const float* e_bih0  = (const float*)d_in[8];
  const float* e_bhh0  = (const float*)d_in[9];
  const float* e_wih1  = (const float*)d_in[10];
  const float* e_whh1  = (const float*)d_in[11];
  const float* e_bih1  = (const float*)d_in[12];
  const float* e_bhh1  = (const float*)d_in[13];
  const float* d_wih0  = (const float*)d_in[14];
  const float* d_whh0  = (const float*)d_in[15];
  const float* d_bih0  = (const float*)d_in[16];
  const float* d_bhh0  = (const float*)d_in[17];
  const float* d_wih1  = (const float*)d_in[18];
  const float* d_whh1  = (const float*)d_in[19];
  const float* d_bih1  = (const float*)d_in[20];
  const float* d_bhh1  = (const float*)d_in[21];

  float* out = (float*)d_out;
  float* wsf = (float*)d_ws;

  float* ys0 = wsf;                         // [2][B][H]
  float* h1e = ys0 + 2 * BH;                // [2][B][H]
  float* h0d = h1e + 2 * BH;                // [2][B][H]
  float* h1d = h0d + 2 * BH;                // [2][B][H]
  float* c0  = h1d + 2 * BH;                // [B][H]
  float* c1  = c0 + BH;                     // [B][H]
  u64*   packed = (u64*)(c1 + BH);          // [T][B][8]

  ki<<<512, 256, 0, stream>>>(packed, out);

  for (int t = 0; t <= T; ++t)
    ke<<<1024, 256, 0, stream>>>(t, src, emb_enc,
                                 e_wih0, e_whh0, e_bih0, e_bhh0,
                                 e_wih1, e_whh1, e_bih1, e_bhh1,
                                 ys0, h1e, c0, c1);

  for (int t = 1; t < T; ++t) {
    ka<<<512, 256, 0, stream>>>(t, src, tfm, packed, emb_dec,
                                d_wih0, d_whh0, d_bih0, d_bhh0,
                                ys0, h0d, c0);
    kb<<<512, 256, 0, stream>>>(t, d_wih1, d_whh1, d_bih1, d_bhh1,
                                h0d, h1e, h1d, c1);
    kf<<<500, 256, 0, stream>>>(t, fc_w, fc_b, h1d, out, packed);
  }
}